// Round 1
// baseline (81.046 us; speedup 1.0000x reference)
//
#include <hip/hip_runtime.h>
#include <math.h>

#define BB    8
#define NN    4096
#define DIRS  2
#define TPB   256
#define Q     4                 // queries per thread (register-resident)
#define QPB   (TPB * Q)         // 1024 queries per block
#define QC    (NN / QPB)        // 4 query chunks
#define RSIZE 512               // refs per block (LDS-staged)
#define RC    (NN / RSIZE)      // 8 ref chunks
#define CDN   (DIRS * BB * NN)  // 65536 query slots (both directions)
#define RBLK  64                // reduce blocks

// --- Kernel 1: brute-force chamfer partial mins --------------------------
// d2 = |q - r|^2 = q^2 + (r^2 - 2 q.r). We track min over refs of
// (r^2 - 2 q.r) with (-2rx, -2ry, r^2) staged in LDS -> 3 VALU per pair.
__global__ __launch_bounds__(TPB) void chamfer_kernel(
    const float* __restrict__ y_true, const float* __restrict__ y_pred,
    float* __restrict__ part)
{
    __shared__ float4 refs[RSIZE];
    const int qc  = blockIdx.x % QC;
    const int rc  = blockIdx.x / QC;
    const int dir = blockIdx.y;     // 0: true->pred, 1: pred->true
    const int b   = blockIdx.z;

    const float2* qbase = (const float2*)(dir == 0 ? y_true : y_pred) + (size_t)b * NN;
    const float2* rbase = (const float2*)(dir == 0 ? y_pred : y_true) + (size_t)b * NN;

    const int t = threadIdx.x;
    #pragma unroll
    for (int k = t; k < RSIZE; k += TPB) {
        float2 r = rbase[rc * RSIZE + k];
        refs[k] = make_float4(-2.f * r.x, -2.f * r.y,
                              r.x * r.x + r.y * r.y, 0.f);
    }
    __syncthreads();

    float qx[Q], qy[Q], m[Q];
    #pragma unroll
    for (int j = 0; j < Q; ++j) {
        float2 qv = qbase[qc * QPB + j * TPB + t];
        qx[j] = qv.x; qy[j] = qv.y; m[j] = INFINITY;
    }

    #pragma unroll 4
    for (int k = 0; k < RSIZE; ++k) {
        float4 r = refs[k];
        #pragma unroll
        for (int j = 0; j < Q; ++j) {
            float d = fmaf(qy[j], r.y, fmaf(qx[j], r.x, r.z));
            m[j] = fminf(m[j], d);
        }
    }

    #pragma unroll
    for (int j = 0; j < Q; ++j) {
        int q = qc * QPB + j * TPB + t;
        float v = fmaxf(m[j] + (qx[j] * qx[j] + qy[j] * qy[j]), 0.f);
        // layout: part[rc][dir][b][q]  ==  rc*CDN + (dir*BB + b)*NN + q
        part[(size_t)rc * CDN + ((size_t)dir * BB + b) * NN + q] = v;
    }
}

// --- Kernel 2: combine partials + EMD, block partial sums ----------------
__global__ __launch_bounds__(TPB) void reduce_kernel(
    const float* __restrict__ y_true, const float* __restrict__ y_pred,
    const float* __restrict__ part, float* __restrict__ blocksum)
{
    const float cd_scale  = 1.0f / (float)BB;
    const float emd_scale = 1.0f / (2.0f * (float)BB * (float)NN);

    float acc = 0.f;
    const int gsz = gridDim.x * blockDim.x;
    const int gid = blockIdx.x * blockDim.x + threadIdx.x;

    for (int i = gid; i < CDN; i += gsz) {
        float mv = part[i];
        #pragma unroll
        for (int rc = 1; rc < RC; ++rc)
            mv = fminf(mv, part[(size_t)rc * CDN + i]);
        acc += mv * cd_scale;
    }

    const float2* tp = (const float2*)y_true;
    const float2* pp = (const float2*)y_pred;
    for (int i = gid; i < BB * NN; i += gsz) {
        float2 tv = tp[i], pv = pp[i];
        float c1 = tv.x - pv.x;                      // cumsum[0] diff
        float c2 = (tv.x + tv.y) - (pv.x + pv.y);    // cumsum[1] diff
        acc = fmaf(c1 * emd_scale, c1, acc);
        acc = fmaf(c2 * emd_scale, c2, acc);
    }

    #pragma unroll
    for (int off = 32; off > 0; off >>= 1)
        acc += __shfl_down(acc, off, 64);

    __shared__ float wsum[TPB / 64];
    const int lane = threadIdx.x & 63, wid = threadIdx.x >> 6;
    if (lane == 0) wsum[wid] = acc;
    __syncthreads();
    if (threadIdx.x == 0) {
        float s = 0.f;
        #pragma unroll
        for (int w = 0; w < TPB / 64; ++w) s += wsum[w];
        blocksum[blockIdx.x] = s;
    }
}

// --- Kernel 3: final 64-element sum --------------------------------------
__global__ void final_kernel(const float* __restrict__ blocksum,
                             float* __restrict__ out)
{
    float v = blocksum[threadIdx.x];
    #pragma unroll
    for (int off = 32; off > 0; off >>= 1)
        v += __shfl_down(v, off, 64);
    if (threadIdx.x == 0) out[0] = v;
}

extern "C" void kernel_launch(void* const* d_in, const int* in_sizes, int n_in,
                              void* d_out, int out_size, void* d_ws, size_t ws_size,
                              hipStream_t stream) {
    const float* y_true = (const float*)d_in[0];
    const float* y_pred = (const float*)d_in[1];
    float* out = (float*)d_out;

    float* part     = (float*)d_ws;                 // RC*CDN floats = 2 MiB
    float* blocksum = part + (size_t)RC * CDN;      // RBLK floats

    chamfer_kernel<<<dim3(QC * RC, DIRS, BB), TPB, 0, stream>>>(y_true, y_pred, part);
    reduce_kernel<<<RBLK, TPB, 0, stream>>>(y_true, y_pred, part, blocksum);
    final_kernel<<<1, 64, 0, stream>>>(blocksum, out);
}

// Round 2
// 80.926 us; speedup vs baseline: 1.0015x; 1.0015x over previous
//
#include <hip/hip_runtime.h>
#include <math.h>

#define BB    8
#define NN    4096
#define DIRS  2
#define TPB   256
#define Q     16                // queries per thread (register-resident)
#define RSIZE 128               // refs per block (LDS-staged)
#define RC    (NN / RSIZE)      // 32 ref chunks
#define CDN   (DIRS * BB * NN)  // 65536 query slots (both directions)
#define RBLK  128               // reduce blocks

// --- Kernel 1: brute-force chamfer partial mins --------------------------
// d2 = |q - r|^2 = q^2 + (r^2 - 2 q.r). Track min over refs of
// (r^2 - 2 q.r) with (-2rx, -2ry, r^2) staged in LDS.
// Q=16 queries/thread so each ds_read_b128 broadcast feeds 48 VALU ops:
// LDS pipe at ~50%, VALU at its floor (3 ops/pair).
__global__ __launch_bounds__(TPB) void chamfer_kernel(
    const float* __restrict__ y_true, const float* __restrict__ y_pred,
    float* __restrict__ part)
{
    __shared__ float4 refs[RSIZE];
    const int rc  = blockIdx.x;     // ref chunk
    const int dir = blockIdx.y;     // 0: true->pred, 1: pred->true
    const int b   = blockIdx.z;

    const float2* qbase = (const float2*)(dir == 0 ? y_true : y_pred) + (size_t)b * NN;
    const float2* rbase = (const float2*)(dir == 0 ? y_pred : y_true) + (size_t)b * NN;

    const int t = threadIdx.x;
    if (t < RSIZE) {
        float2 r = rbase[rc * RSIZE + t];
        refs[t] = make_float4(-2.f * r.x, -2.f * r.y,
                              r.x * r.x + r.y * r.y, 0.f);
    }
    __syncthreads();

    float qx[Q], qy[Q], m[Q];
    #pragma unroll
    for (int j = 0; j < Q; ++j) {
        float2 qv = qbase[j * TPB + t];          // Q*TPB == NN, coalesced
        qx[j] = qv.x; qy[j] = qv.y; m[j] = INFINITY;
    }

    #pragma unroll 4
    for (int k = 0; k < RSIZE; ++k) {
        float4 r = refs[k];
        #pragma unroll
        for (int j = 0; j < Q; ++j) {
            float d = fmaf(qy[j], r.y, fmaf(qx[j], r.x, r.z));
            m[j] = fminf(m[j], d);
        }
    }

    #pragma unroll
    for (int j = 0; j < Q; ++j) {
        int q = j * TPB + t;
        float v = fmaxf(m[j] + (qx[j] * qx[j] + qy[j] * qy[j]), 0.f);
        // layout: part[rc][dir][b][q]  ==  rc*CDN + (dir*BB + b)*NN + q
        part[(size_t)rc * CDN + ((size_t)dir * BB + b) * NN + q] = v;
    }
}

// --- Kernel 2: combine partials + EMD, block partial sums ----------------
__global__ __launch_bounds__(TPB) void reduce_kernel(
    const float* __restrict__ y_true, const float* __restrict__ y_pred,
    const float* __restrict__ part, float* __restrict__ blocksum)
{
    const float cd_scale  = 1.0f / (float)BB;
    const float emd_scale = 1.0f / (2.0f * (float)BB * (float)NN);

    float acc = 0.f;
    const int gsz = gridDim.x * blockDim.x;
    const int gid = blockIdx.x * blockDim.x + threadIdx.x;

    for (int i = gid; i < CDN; i += gsz) {
        float mv = part[i];
        #pragma unroll
        for (int rc = 1; rc < RC; ++rc)
            mv = fminf(mv, part[(size_t)rc * CDN + i]);
        acc += mv * cd_scale;
    }

    const float2* tp = (const float2*)y_true;
    const float2* pp = (const float2*)y_pred;
    for (int i = gid; i < BB * NN; i += gsz) {
        float2 tv = tp[i], pv = pp[i];
        float c1 = tv.x - pv.x;                      // cumsum[0] diff
        float c2 = (tv.x + tv.y) - (pv.x + pv.y);    // cumsum[1] diff
        acc = fmaf(c1 * emd_scale, c1, acc);
        acc = fmaf(c2 * emd_scale, c2, acc);
    }

    #pragma unroll
    for (int off = 32; off > 0; off >>= 1)
        acc += __shfl_down(acc, off, 64);

    __shared__ float wsum[TPB / 64];
    const int lane = threadIdx.x & 63, wid = threadIdx.x >> 6;
    if (lane == 0) wsum[wid] = acc;
    __syncthreads();
    if (threadIdx.x == 0) {
        float s = 0.f;
        #pragma unroll
        for (int w = 0; w < TPB / 64; ++w) s += wsum[w];
        blocksum[blockIdx.x] = s;
    }
}

// --- Kernel 3: final sum over RBLK block partials ------------------------
__global__ void final_kernel(const float* __restrict__ blocksum,
                             float* __restrict__ out)
{
    float v = blocksum[threadIdx.x] + blocksum[threadIdx.x + 64];
    #pragma unroll
    for (int off = 32; off > 0; off >>= 1)
        v += __shfl_down(v, off, 64);
    if (threadIdx.x == 0) out[0] = v;
}

extern "C" void kernel_launch(void* const* d_in, const int* in_sizes, int n_in,
                              void* d_out, int out_size, void* d_ws, size_t ws_size,
                              hipStream_t stream) {
    const float* y_true = (const float*)d_in[0];
    const float* y_pred = (const float*)d_in[1];
    float* out = (float*)d_out;

    float* part     = (float*)d_ws;                 // RC*CDN floats = 8 MiB
    float* blocksum = part + (size_t)RC * CDN;      // RBLK floats

    chamfer_kernel<<<dim3(RC, DIRS, BB), TPB, 0, stream>>>(y_true, y_pred, part);
    reduce_kernel<<<RBLK, TPB, 0, stream>>>(y_true, y_pred, part, blocksum);
    final_kernel<<<1, 64, 0, stream>>>(blocksum, out);
}